// Round 1
// baseline (1069.455 us; speedup 1.0000x reference)
//
#include <hip/hip_runtime.h>

#define N_NODES 50000
#define N_EDGES 600000
#define DIM 128

// ---------------- GEMM: h[n][j] = sum_k x[n][k] * W[j][k] ----------------
// Block: 256 threads. 64 rows per block. Thread computes 8 rows x 4 cols.
// K is processed in two halves of 64 so LDS stays under the 64KB static limit.
// LDS strides of 66 floats give 2-way (free) bank aliasing on b64 reads.
#define KH 64          // k half-width
#define GS 66          // padded LDS stride (floats) for a k-half

__global__ __launch_bounds__(256) void gemm_kernel(const float* __restrict__ x,
                                                   const float* __restrict__ W,
                                                   float* __restrict__ h) {
    __shared__ float Ws[DIM * GS];   // 128 x 66 floats = 33792 B
    __shared__ float Xs[64 * GS];    //  64 x 66 floats = 16896 B
    const int tid = threadIdx.x;
    const int tj  = tid & 31;        // j-lane: owns j = tj + 32*jj
    const int tr  = tid >> 5;        // row group: owns rows tr*8 .. tr*8+7
    const int row0 = blockIdx.x * 64;

    float acc[8][4];
#pragma unroll
    for (int a = 0; a < 8; ++a)
#pragma unroll
        for (int b = 0; b < 4; ++b) acc[a][b] = 0.f;

    for (int kh = 0; kh < 2; ++kh) {
        // ---- stage W k-half: 128 rows x 64 floats = 4096 float2, 16/thread
#pragma unroll
        for (int i = 0; i < 16; ++i) {
            int l = tid + i * 256;       // float2 index
            int r = l >> 5;              // 32 float2 per row
            int c = (l & 31) << 1;
            float2 v = *reinterpret_cast<const float2*>(&W[r * DIM + kh * KH + c]);
            *reinterpret_cast<float2*>(&Ws[r * GS + c]) = v;
        }
        // ---- stage x tile k-half: 64 rows x 64 floats = 2048 float2, 8/thread
#pragma unroll
        for (int i = 0; i < 8; ++i) {
            int l = tid + i * 256;
            int r = l >> 5;
            int c = (l & 31) << 1;
            int gr = row0 + r; if (gr >= N_NODES) gr = N_NODES - 1;
            float2 v = *reinterpret_cast<const float2*>(&x[gr * DIM + kh * KH + c]);
            *reinterpret_cast<float2*>(&Xs[r * GS + c]) = v;
        }
        __syncthreads();

        for (int k2 = 0; k2 < 32; ++k2) {
            float2 xv[8], wv[4];
#pragma unroll
            for (int rr = 0; rr < 8; ++rr)
                xv[rr] = *reinterpret_cast<const float2*>(&Xs[(tr * 8 + rr) * GS + k2 * 2]);
#pragma unroll
            for (int jj = 0; jj < 4; ++jj)
                wv[jj] = *reinterpret_cast<const float2*>(&Ws[(tj + jj * 32) * GS + k2 * 2]);
#pragma unroll
            for (int rr = 0; rr < 8; ++rr)
#pragma unroll
                for (int jj = 0; jj < 4; ++jj)
                    acc[rr][jj] += wv[jj].x * xv[rr].x + wv[jj].y * xv[rr].y;
        }
        __syncthreads();
    }

#pragma unroll
    for (int rr = 0; rr < 8; ++rr) {
        int gr = row0 + tr * 8 + rr;
        if (gr < N_NODES) {
#pragma unroll
            for (int jj = 0; jj < 4; ++jj)
                h[(long long)gr * DIM + tj + jj * 32] = acc[rr][jj];
        }
    }
}

// ---------------- Edge scatter: out[row] += val * h[col] ----------------
// 32 lanes per edge, each lane handles a float4 (16B): 32*16 = 512B = 128 floats.
__global__ __launch_bounds__(256) void edge_kernel(const float* __restrict__ h,
                                                   const float* __restrict__ vals,
                                                   const int* __restrict__ rows,
                                                   const int* __restrict__ cols,
                                                   float* __restrict__ out) {
    long long gid = (long long)blockIdx.x * 256 + threadIdx.x;
    int e    = (int)(gid >> 5);
    int lane = (int)(gid & 31);
    if (e >= N_EDGES) return;
    int r = rows[e];
    int c = cols[e];
    float v = vals[e];
    float4 hv = *reinterpret_cast<const float4*>(&h[(long long)c * DIM + lane * 4]);
    float* op = &out[(long long)r * DIM + lane * 4];
    atomicAdd(op + 0, v * hv.x);
    atomicAdd(op + 1, v * hv.y);
    atomicAdd(op + 2, v * hv.z);
    atomicAdd(op + 3, v * hv.w);
}

// ---------------- ReLU in-place ----------------
__global__ __launch_bounds__(256) void relu_kernel(float* __restrict__ out) {
    int i = blockIdx.x * 256 + threadIdx.x;
    float4* p = reinterpret_cast<float4*>(out) + i;   // grid sized exactly
    float4 v = *p;
    v.x = fmaxf(v.x, 0.f);
    v.y = fmaxf(v.y, 0.f);
    v.z = fmaxf(v.z, 0.f);
    v.w = fmaxf(v.w, 0.f);
    *p = v;
}

extern "C" void kernel_launch(void* const* d_in, const int* in_sizes, int n_in,
                              void* d_out, int out_size, void* d_ws, size_t ws_size,
                              hipStream_t stream) {
    const float* x    = (const float*)d_in[0];
    const float* W    = (const float*)d_in[1];
    const float* vals = (const float*)d_in[2];
    const int*   rows = (const int*)d_in[3];
    const int*   cols = (const int*)d_in[4];
    float* out = (float*)d_out;
    float* h   = (float*)d_ws;   // 50000*128*4 = 25.6 MB scratch

    // h = x @ W^T
    gemm_kernel<<<(N_NODES + 63) / 64, 256, 0, stream>>>(x, W, h);
    // out = 0
    hipMemsetAsync(d_out, 0, (size_t)N_NODES * DIM * sizeof(float), stream);
    // out[row] += val * h[col]
    edge_kernel<<<(N_EDGES * 32) / 256, 256, 0, stream>>>(h, vals, rows, cols, out);
    // out = relu(out)
    relu_kernel<<<(N_NODES * DIM / 4) / 256, 256, 0, stream>>>(out);
}

// Round 2
// 210.178 us; speedup vs baseline: 5.0883x; 5.0883x over previous
//
#include <hip/hip_runtime.h>

#define N_NODES 50000
#define N_EDGES 600000
#define DIM 128
#define SCAN_BLK 256
#define NSCAN ((N_NODES + SCAN_BLK - 1) / SCAN_BLK)   // 196 scan blocks

// ---------------- GEMM: h[n][j] = sum_k x[n][k] * W[j][k] ----------------
#define KH 64
#define GS 66

__global__ __launch_bounds__(256) void gemm_kernel(const float* __restrict__ x,
                                                   const float* __restrict__ W,
                                                   float* __restrict__ h) {
    __shared__ float Ws[DIM * GS];
    __shared__ float Xs[64 * GS];
    const int tid = threadIdx.x;
    const int tj  = tid & 31;
    const int tr  = tid >> 5;
    const int row0 = blockIdx.x * 64;

    float acc[8][4];
#pragma unroll
    for (int a = 0; a < 8; ++a)
#pragma unroll
        for (int b = 0; b < 4; ++b) acc[a][b] = 0.f;

    for (int kh = 0; kh < 2; ++kh) {
#pragma unroll
        for (int i = 0; i < 16; ++i) {
            int l = tid + i * 256;
            int r = l >> 5;
            int c = (l & 31) << 1;
            float2 v = *reinterpret_cast<const float2*>(&W[r * DIM + kh * KH + c]);
            *reinterpret_cast<float2*>(&Ws[r * GS + c]) = v;
        }
#pragma unroll
        for (int i = 0; i < 8; ++i) {
            int l = tid + i * 256;
            int r = l >> 5;
            int c = (l & 31) << 1;
            int gr = row0 + r; if (gr >= N_NODES) gr = N_NODES - 1;
            float2 v = *reinterpret_cast<const float2*>(&x[gr * DIM + kh * KH + c]);
            *reinterpret_cast<float2*>(&Xs[r * GS + c]) = v;
        }
        __syncthreads();

        for (int k2 = 0; k2 < 32; ++k2) {
            float2 xv[8], wv[4];
#pragma unroll
            for (int rr = 0; rr < 8; ++rr)
                xv[rr] = *reinterpret_cast<const float2*>(&Xs[(tr * 8 + rr) * GS + k2 * 2]);
#pragma unroll
            for (int jj = 0; jj < 4; ++jj)
                wv[jj] = *reinterpret_cast<const float2*>(&Ws[(tj + jj * 32) * GS + k2 * 2]);
#pragma unroll
            for (int rr = 0; rr < 8; ++rr)
#pragma unroll
                for (int jj = 0; jj < 4; ++jj)
                    acc[rr][jj] += wv[jj].x * xv[rr].x + wv[jj].y * xv[rr].y;
        }
        __syncthreads();
    }

#pragma unroll
    for (int rr = 0; rr < 8; ++rr) {
        int gr = row0 + tr * 8 + rr;
        if (gr < N_NODES) {
#pragma unroll
            for (int jj = 0; jj < 4; ++jj)
                h[(long long)gr * DIM + tj + jj * 32] = acc[rr][jj];
        }
    }
}

// ---------------- CSR build ----------------
__global__ __launch_bounds__(256) void hist_kernel(const int* __restrict__ rows,
                                                   int* __restrict__ cnt) {
    int e = blockIdx.x * 256 + threadIdx.x;
    if (e < N_EDGES) atomicAdd(&cnt[rows[e]], 1);
}

__global__ __launch_bounds__(SCAN_BLK) void scan1_kernel(const int* __restrict__ cnt,
                                                         int* __restrict__ off,
                                                         int* __restrict__ bsum) {
    __shared__ int s[SCAN_BLK];
    int t = threadIdx.x;
    int i = blockIdx.x * SCAN_BLK + t;
    int v = (i < N_NODES) ? cnt[i] : 0;
    s[t] = v;
    __syncthreads();
    for (int d = 1; d < SCAN_BLK; d <<= 1) {
        int add = (t >= d) ? s[t - d] : 0;
        __syncthreads();
        s[t] += add;
        __syncthreads();
    }
    if (i < N_NODES) off[i] = s[t] - v;          // exclusive within block
    if (t == SCAN_BLK - 1) bsum[blockIdx.x] = s[t];
}

__global__ __launch_bounds__(SCAN_BLK) void scan2_kernel(int* __restrict__ bsum) {
    __shared__ int s[SCAN_BLK];
    int t = threadIdx.x;
    int v = (t < NSCAN) ? bsum[t] : 0;
    s[t] = v;
    __syncthreads();
    for (int d = 1; d < SCAN_BLK; d <<= 1) {
        int add = (t >= d) ? s[t - d] : 0;
        __syncthreads();
        s[t] += add;
        __syncthreads();
    }
    if (t < NSCAN) bsum[t] = s[t] - v;           // exclusive
}

__global__ __launch_bounds__(SCAN_BLK) void scan3_kernel(int* __restrict__ off,
                                                         const int* __restrict__ bsum) {
    int i = blockIdx.x * SCAN_BLK + threadIdx.x;
    if (i < N_NODES) off[i] += bsum[blockIdx.x];
    if (blockIdx.x == 0 && threadIdx.x == 0) off[N_NODES] = N_EDGES;
}

__global__ __launch_bounds__(256) void scatter_kernel(const int* __restrict__ rows,
                                                      const int* __restrict__ off,
                                                      int* __restrict__ cnt,
                                                      int* __restrict__ order) {
    int e = blockIdx.x * 256 + threadIdx.x;
    if (e >= N_EDGES) return;
    int r = rows[e];
    int p = atomicAdd(&cnt[r], 1);
    order[off[r] + p] = e;
}

// ---------------- Gather: one wave per node, fused ReLU ----------------
__global__ __launch_bounds__(256) void gather_kernel(const float* __restrict__ h,
                                                     const float* __restrict__ vals,
                                                     const int* __restrict__ cols,
                                                     const int* __restrict__ off,
                                                     const int* __restrict__ order,
                                                     float* __restrict__ out) {
    int wave = threadIdx.x >> 6;
    int lane = threadIdx.x & 63;
    int n = blockIdx.x * 4 + wave;
    if (n >= N_NODES) return;
    int beg = off[n], end = off[n + 1];
    float ax = 0.f, ay = 0.f;
    for (int i = beg; i < end; ++i) {
        int e = order[i];
        int c = cols[e];
        float v = vals[e];
        float2 hv = *reinterpret_cast<const float2*>(&h[(size_t)c * DIM + lane * 2]);
        ax += v * hv.x;
        ay += v * hv.y;
    }
    float2 r;
    r.x = fmaxf(ax, 0.f);
    r.y = fmaxf(ay, 0.f);
    *reinterpret_cast<float2*>(&out[(size_t)n * DIM + lane * 2]) = r;
}

// ---------------- Fallback (round-0 atomic path) ----------------
__global__ __launch_bounds__(256) void edge_kernel(const float* __restrict__ h,
                                                   const float* __restrict__ vals,
                                                   const int* __restrict__ rows,
                                                   const int* __restrict__ cols,
                                                   float* __restrict__ out) {
    long long gid = (long long)blockIdx.x * 256 + threadIdx.x;
    int e    = (int)(gid >> 5);
    int lane = (int)(gid & 31);
    if (e >= N_EDGES) return;
    int r = rows[e];
    int c = cols[e];
    float v = vals[e];
    float4 hv = *reinterpret_cast<const float4*>(&h[(long long)c * DIM + lane * 4]);
    float* op = &out[(long long)r * DIM + lane * 4];
    atomicAdd(op + 0, v * hv.x);
    atomicAdd(op + 1, v * hv.y);
    atomicAdd(op + 2, v * hv.z);
    atomicAdd(op + 3, v * hv.w);
}

__global__ __launch_bounds__(256) void relu_kernel(float* __restrict__ out) {
    int i = blockIdx.x * 256 + threadIdx.x;
    float4* p = reinterpret_cast<float4*>(out) + i;
    float4 v = *p;
    v.x = fmaxf(v.x, 0.f);
    v.y = fmaxf(v.y, 0.f);
    v.z = fmaxf(v.z, 0.f);
    v.w = fmaxf(v.w, 0.f);
    *p = v;
}

extern "C" void kernel_launch(void* const* d_in, const int* in_sizes, int n_in,
                              void* d_out, int out_size, void* d_ws, size_t ws_size,
                              hipStream_t stream) {
    const float* x    = (const float*)d_in[0];
    const float* W    = (const float*)d_in[1];
    const float* vals = (const float*)d_in[2];
    const int*   rows = (const int*)d_in[3];
    const int*   cols = (const int*)d_in[4];
    float* out = (float*)d_out;

    // ---- workspace layout ----
    float* h   = (float*)d_ws;                               // 25.6 MB
    int*   cnt = (int*)(h + (size_t)N_NODES * DIM);          // 50000 ints
    int*   off = cnt + N_NODES;                              // 50001 ints
    int*   bsum = off + (N_NODES + 1);                       // NSCAN ints
    int*   order = bsum + NSCAN;                             // 600000 ints
    size_t need = (size_t)((char*)(order + N_EDGES) - (char*)d_ws);

    // h = x @ W^T
    gemm_kernel<<<(N_NODES + 63) / 64, 256, 0, stream>>>(x, W, h);

    if (ws_size >= need) {
        // ---- CSR build ----
        hipMemsetAsync(cnt, 0, N_NODES * sizeof(int), stream);
        hist_kernel<<<(N_EDGES + 255) / 256, 256, 0, stream>>>(rows, cnt);
        scan1_kernel<<<NSCAN, SCAN_BLK, 0, stream>>>(cnt, off, bsum);
        scan2_kernel<<<1, SCAN_BLK, 0, stream>>>(bsum);
        scan3_kernel<<<NSCAN, SCAN_BLK, 0, stream>>>(off, bsum);
        hipMemsetAsync(cnt, 0, N_NODES * sizeof(int), stream);
        scatter_kernel<<<(N_EDGES + 255) / 256, 256, 0, stream>>>(rows, off, cnt, order);
        // ---- gather + relu, one wave per node ----
        gather_kernel<<<(N_NODES + 3) / 4, 256, 0, stream>>>(h, vals, cols, off, order, out);
    } else {
        // fallback: atomic scatter
        hipMemsetAsync(d_out, 0, (size_t)N_NODES * DIM * sizeof(float), stream);
        edge_kernel<<<(N_EDGES * 32) / 256, 256, 0, stream>>>(h, vals, rows, cols, out);
        relu_kernel<<<(N_NODES * DIM / 4) / 256, 256, 0, stream>>>(out);
    }
}

// Round 3
// 146.225 us; speedup vs baseline: 7.3138x; 1.4374x over previous
//
#include <hip/hip_runtime.h>

#define N_NODES 50000
#define N_EDGES 600000
#define DIM 128
#define SCAN_BLK 256
#define NSCAN ((N_NODES + SCAN_BLK - 1) / SCAN_BLK)   // 196

__device__ __forceinline__ float bf2f(unsigned short u) {
    union { unsigned int i; float f; } x; x.i = ((unsigned int)u) << 16; return x.f;
}
__device__ __forceinline__ unsigned short f2bf(float f) {
    union { float f; unsigned int i; } x; x.f = f;
    unsigned int r = x.i + 0x7FFFu + ((x.i >> 16) & 1u);   // RNE
    return (unsigned short)(r >> 16);
}

// ---------------- GEMM (+fused row histogram): h[n][j] = sum_k x[n][k]*W[j][k], bf16 out
#define KH 64
#define GS 66
#define GEMM_BLOCKS ((N_NODES + 63) / 64)           // 782
#define GEMM_THREADS (GEMM_BLOCKS * 256)            // 200192

__global__ __launch_bounds__(256) void gemm_kernel(const float* __restrict__ x,
                                                   const float* __restrict__ W,
                                                   unsigned short* __restrict__ h,
                                                   const int* __restrict__ rows,
                                                   int* __restrict__ cnt) {
    __shared__ float Ws[DIM * GS];
    __shared__ float Xs[64 * GS];
    const int tid = threadIdx.x;

    // ---- fused histogram: fire-and-forget atomics, hidden under the GEMM
    {
        int g = blockIdx.x * 256 + tid;
        for (int e = g; e < N_EDGES; e += GEMM_THREADS)
            atomicAdd(&cnt[rows[e]], 1);
    }

    const int tj  = tid & 31;
    const int tr  = tid >> 5;
    const int row0 = blockIdx.x * 64;

    float acc[8][4];
#pragma unroll
    for (int a = 0; a < 8; ++a)
#pragma unroll
        for (int b = 0; b < 4; ++b) acc[a][b] = 0.f;

    for (int kh = 0; kh < 2; ++kh) {
#pragma unroll
        for (int i = 0; i < 16; ++i) {
            int l = tid + i * 256;
            int r = l >> 5;
            int c = (l & 31) << 1;
            float2 v = *reinterpret_cast<const float2*>(&W[r * DIM + kh * KH + c]);
            *reinterpret_cast<float2*>(&Ws[r * GS + c]) = v;
        }
#pragma unroll
        for (int i = 0; i < 8; ++i) {
            int l = tid + i * 256;
            int r = l >> 5;
            int c = (l & 31) << 1;
            int gr = row0 + r; if (gr >= N_NODES) gr = N_NODES - 1;
            float2 v = *reinterpret_cast<const float2*>(&x[gr * DIM + kh * KH + c]);
            *reinterpret_cast<float2*>(&Xs[r * GS + c]) = v;
        }
        __syncthreads();

        for (int k2 = 0; k2 < 32; ++k2) {
            float2 xv[8], wv[4];
#pragma unroll
            for (int rr = 0; rr < 8; ++rr)
                xv[rr] = *reinterpret_cast<const float2*>(&Xs[(tr * 8 + rr) * GS + k2 * 2]);
#pragma unroll
            for (int jj = 0; jj < 4; ++jj)
                wv[jj] = *reinterpret_cast<const float2*>(&Ws[(tj + jj * 32) * GS + k2 * 2]);
#pragma unroll
            for (int rr = 0; rr < 8; ++rr)
#pragma unroll
                for (int jj = 0; jj < 4; ++jj)
                    acc[rr][jj] += wv[jj].x * xv[rr].x + wv[jj].y * xv[rr].y;
        }
        __syncthreads();
    }

#pragma unroll
    for (int rr = 0; rr < 8; ++rr) {
        int gr = row0 + tr * 8 + rr;
        if (gr < N_NODES) {
#pragma unroll
            for (int jj = 0; jj < 4; ++jj)
                h[(size_t)gr * DIM + tj + jj * 32] = f2bf(acc[rr][jj]);
        }
    }
}

// ---------------- scan1: per-block exclusive scan of cnt -> off, block sums -> bsum, re-zero cnt
__global__ __launch_bounds__(SCAN_BLK) void scan1_kernel(int* __restrict__ cnt,
                                                         int* __restrict__ off,
                                                         int* __restrict__ bsum) {
    __shared__ int s[SCAN_BLK];
    int t = threadIdx.x;
    int i = blockIdx.x * SCAN_BLK + t;
    int v = (i < N_NODES) ? cnt[i] : 0;
    if (i < N_NODES) cnt[i] = 0;                 // re-zero for scatter pass
    s[t] = v;
    __syncthreads();
    for (int d = 1; d < SCAN_BLK; d <<= 1) {
        int add = (t >= d) ? s[t - d] : 0;
        __syncthreads();
        s[t] += add;
        __syncthreads();
    }
    if (i < N_NODES) off[i] = s[t] - v;          // exclusive within block
    if (t == SCAN_BLK - 1) bsum[blockIdx.x] = s[t];
}

// ---------------- scan2: exclusive scan of the 196 block sums (single block)
__global__ __launch_bounds__(SCAN_BLK) void scan2_kernel(int* __restrict__ bsum) {
    __shared__ int s[SCAN_BLK];
    int t = threadIdx.x;
    int v = (t < NSCAN) ? bsum[t] : 0;
    s[t] = v;
    __syncthreads();
    for (int d = 1; d < SCAN_BLK; d <<= 1) {
        int add = (t >= d) ? s[t - d] : 0;
        __syncthreads();
        s[t] += add;
        __syncthreads();
    }
    if (t < NSCAN) bsum[t] = s[t] - v;           // exclusive
}

// ---------------- scatter: pack {col, val} into CSR order
__global__ __launch_bounds__(256) void scatter_kernel(const int* __restrict__ rows,
                                                      const int* __restrict__ cols,
                                                      const float* __restrict__ vals,
                                                      const int* __restrict__ off,
                                                      const int* __restrict__ bsum,
                                                      int* __restrict__ cnt,
                                                      int2* __restrict__ epack) {
    int e = blockIdx.x * 256 + threadIdx.x;
    if (e >= N_EDGES) return;
    int r = rows[e];
    int p = atomicAdd(&cnt[r], 1);
    int2 pk;
    pk.x = cols[e];
    pk.y = __float_as_int(vals[e]);
    epack[off[r] + bsum[r >> 8] + p] = pk;
}

// ---------------- gather: one wave per node, 4-deep pipelined, fused ReLU
__global__ __launch_bounds__(256) void gather_kernel(const unsigned short* __restrict__ h,
                                                     const int2* __restrict__ epack,
                                                     const int* __restrict__ off,
                                                     const int* __restrict__ bsum,
                                                     float* __restrict__ out) {
    int wave = threadIdx.x >> 6;
    int lane = threadIdx.x & 63;
    int n = blockIdx.x * 4 + wave;
    if (n >= N_NODES) return;
    int beg = off[n] + bsum[n >> 8];
    int end = (n + 1 < N_NODES) ? off[n + 1] + bsum[(n + 1) >> 8] : N_EDGES;

    float ax = 0.f, ay = 0.f;
    int i = beg;
    for (; i + 4 <= end; i += 4) {
        int2 e0 = epack[i], e1 = epack[i + 1], e2 = epack[i + 2], e3 = epack[i + 3];
        ushort2 a0 = *((const ushort2*)(h + (size_t)e0.x * DIM) + lane);
        ushort2 a1 = *((const ushort2*)(h + (size_t)e1.x * DIM) + lane);
        ushort2 a2 = *((const ushort2*)(h + (size_t)e2.x * DIM) + lane);
        ushort2 a3 = *((const ushort2*)(h + (size_t)e3.x * DIM) + lane);
        float v0 = __int_as_float(e0.y), v1 = __int_as_float(e1.y);
        float v2 = __int_as_float(e2.y), v3 = __int_as_float(e3.y);
        ax += v0 * bf2f(a0.x) + v1 * bf2f(a1.x) + v2 * bf2f(a2.x) + v3 * bf2f(a3.x);
        ay += v0 * bf2f(a0.y) + v1 * bf2f(a1.y) + v2 * bf2f(a2.y) + v3 * bf2f(a3.y);
    }
    for (; i < end; ++i) {
        int2 e0 = epack[i];
        ushort2 a0 = *((const ushort2*)(h + (size_t)e0.x * DIM) + lane);
        float v0 = __int_as_float(e0.y);
        ax += v0 * bf2f(a0.x);
        ay += v0 * bf2f(a0.y);
    }
    float2 r;
    r.x = fmaxf(ax, 0.f);
    r.y = fmaxf(ay, 0.f);
    *reinterpret_cast<float2*>(&out[(size_t)n * DIM + lane * 2]) = r;
}

// ---------------- fallback: atomic scatter over bf16 h
__global__ __launch_bounds__(256) void edge_kernel(const unsigned short* __restrict__ h,
                                                   const float* __restrict__ vals,
                                                   const int* __restrict__ rows,
                                                   const int* __restrict__ cols,
                                                   float* __restrict__ out) {
    long long gid = (long long)blockIdx.x * 256 + threadIdx.x;
    int e    = (int)(gid >> 5);
    int lane = (int)(gid & 31);
    if (e >= N_EDGES) return;
    int r = rows[e];
    int c = cols[e];
    float v = vals[e];
    ushort4 hv = *((const ushort4*)(h + (size_t)c * DIM) + lane);
    float* op = &out[(size_t)r * DIM + lane * 4];
    atomicAdd(op + 0, v * bf2f(hv.x));
    atomicAdd(op + 1, v * bf2f(hv.y));
    atomicAdd(op + 2, v * bf2f(hv.z));
    atomicAdd(op + 3, v * bf2f(hv.w));
}

__global__ __launch_bounds__(256) void relu_kernel(float* __restrict__ out) {
    int i = blockIdx.x * 256 + threadIdx.x;
    float4* p = reinterpret_cast<float4*>(out) + i;
    float4 v = *p;
    v.x = fmaxf(v.x, 0.f);
    v.y = fmaxf(v.y, 0.f);
    v.z = fmaxf(v.z, 0.f);
    v.w = fmaxf(v.w, 0.f);
    *p = v;
}

extern "C" void kernel_launch(void* const* d_in, const int* in_sizes, int n_in,
                              void* d_out, int out_size, void* d_ws, size_t ws_size,
                              hipStream_t stream) {
    const float* x    = (const float*)d_in[0];
    const float* W    = (const float*)d_in[1];
    const float* vals = (const float*)d_in[2];
    const int*   rows = (const int*)d_in[3];
    const int*   cols = (const int*)d_in[4];
    float* out = (float*)d_out;

    // ---- workspace layout ----
    unsigned short* h = (unsigned short*)d_ws;               // 12.8 MB bf16
    int2* epack = (int2*)(h + (size_t)N_NODES * DIM);        // 4.8 MB (8B-aligned)
    int*  cnt   = (int*)(epack + N_EDGES);                   // 50000
    int*  off   = cnt + N_NODES;                             // 50000
    int*  bsum  = off + N_NODES;                             // 196
    size_t need = (size_t)((char*)(bsum + NSCAN) - (char*)d_ws);

    if (ws_size >= need) {
        hipMemsetAsync(cnt, 0, N_NODES * sizeof(int), stream);
        // h = bf16(x @ W^T), cnt = row histogram (fused)
        gemm_kernel<<<GEMM_BLOCKS, 256, 0, stream>>>(x, W, h, rows, cnt);
        scan1_kernel<<<NSCAN, SCAN_BLK, 0, stream>>>(cnt, off, bsum);
        scan2_kernel<<<1, SCAN_BLK, 0, stream>>>(bsum);
        scatter_kernel<<<(N_EDGES + 255) / 256, 256, 0, stream>>>(rows, cols, vals, off, bsum, cnt, epack);
        gather_kernel<<<(N_NODES + 3) / 4, 256, 0, stream>>>(h, epack, off, bsum, out);
    } else {
        // fallback: atomic scatter path (needs only h)
        gemm_kernel<<<GEMM_BLOCKS, 256, 0, stream>>>(x, W, h, rows, (int*)(h + (size_t)N_NODES * DIM));
        hipMemsetAsync(d_out, 0, (size_t)N_NODES * DIM * sizeof(float), stream);
        edge_kernel<<<(N_EDGES * 32) / 256, 256, 0, stream>>>(h, vals, rows, cols, out);
        relu_kernel<<<(N_NODES * DIM / 4) / 256, 256, 0, stream>>>(out);
    }
}

// Round 4
// 115.549 us; speedup vs baseline: 9.2554x; 1.2655x over previous
//
#include <hip/hip_runtime.h>

#define N_NODES 50000
#define N_EDGES 600000
#define DIM 128
#define SCAN_BLK 256
#define NSCAN ((N_NODES + SCAN_BLK - 1) / SCAN_BLK)   // 196

typedef short bf16x8 __attribute__((ext_vector_type(8)));
typedef float f32x4 __attribute__((ext_vector_type(4)));

__device__ __forceinline__ float bf2f(unsigned short u) {
    union { unsigned int i; float f; } x; x.i = ((unsigned int)u) << 16; return x.f;
}
__device__ __forceinline__ unsigned short f2bf(float f) {
    union { float f; unsigned int i; } x; x.f = f;
    unsigned int r = x.i + 0x7FFFu + ((x.i >> 16) & 1u);   // RNE
    return (unsigned short)(r >> 16);
}

// ---------------- MFMA GEMM (+fused row histogram) ----------------
// h[n][d] = bf16( sum_k x[n][k] * W[d][k] ), fp32 MFMA accumulate.
// A = W-tile (16 dims x 32 k), B = x-tile (32 k x 16 nodes) so that the C/D
// layout (col=lane&15, row=(lane>>4)*4+reg) puts node on the lane and 4
// CONSECUTIVE dims in the 4 acc regs -> packed coalesced 8B stores.
// W staged once per block in LDS (bf16, XOR-swizzled to kill the stride-256B
// bank conflict on fragment reads). x fragments read straight from global
// (each row read exactly once grid-wide) and converted in-register.
#define GEMM_BLOCKS ((N_NODES + 63) / 64)           // 782
#define GEMM_THREADS (GEMM_BLOCKS * 256)            // 200192

__global__ __launch_bounds__(256) void gemm_kernel(const float* __restrict__ x,
                                                   const float* __restrict__ W,
                                                   unsigned short* __restrict__ h,
                                                   const int* __restrict__ rows,
                                                   int* __restrict__ cnt) {
    __shared__ unsigned char Wl[128 * 256];   // bf16[128 dims][128 k], swizzled
    const int tid = threadIdx.x;

    // ---- fused histogram: fire-and-forget atomics, hidden under the GEMM
    if (cnt) {
        int g = blockIdx.x * 256 + tid;
#pragma unroll
        for (int it = 0; it < 3; ++it) {
            int e = g + it * GEMM_THREADS;
            if (e < N_EDGES) atomicAdd(&cnt[rows[e]], 1);
        }
    }

    // ---- stage W -> LDS bf16 (swizzled): 4096 float4 chunks, 16 per thread
#pragma unroll
    for (int i = 0; i < 16; ++i) {
        int c  = tid + i * 256;
        int od = c >> 5;                 // out dim (W row)
        int kg = c & 31;                 // float4 group: k0 = kg*4
        float4 w = *((const float4*)(W + od * DIM) + kg);
        unsigned int lo = (unsigned int)f2bf(w.x) | ((unsigned int)f2bf(w.y) << 16);
        unsigned int hi = (unsigned int)f2bf(w.z) | ((unsigned int)f2bf(w.w) << 16);
        int byte = od * 256 + ((kg * 8) ^ ((od & 7) << 4));
        *reinterpret_cast<uint2*>(Wl + byte) = make_uint2(lo, hi);
    }

    // ---- load + convert this wave's x rows (node = lane&15, k-slot = lane>>4)
    const int lane = tid & 63;
    const int wv   = tid >> 6;
    const int q    = lane >> 4;
    const int node = blockIdx.x * 64 + wv * 16 + (lane & 15);
    const int ncl  = node < N_NODES ? node : N_NODES - 1;

    bf16x8 xb[4];
#pragma unroll
    for (int s = 0; s < 4; ++s) {
        const float* xp = x + (size_t)ncl * DIM + s * 32 + q * 8;
        float4 x0 = *(const float4*)(xp);
        float4 x1 = *(const float4*)(xp + 4);
        bf16x8 v;
        v[0] = (short)f2bf(x0.x); v[1] = (short)f2bf(x0.y);
        v[2] = (short)f2bf(x0.z); v[3] = (short)f2bf(x0.w);
        v[4] = (short)f2bf(x1.x); v[5] = (short)f2bf(x1.y);
        v[6] = (short)f2bf(x1.z); v[7] = (short)f2bf(x1.w);
        xb[s] = v;
    }

    __syncthreads();

    // ---- 8 dim-tiles x 4 k-steps of mfma_f32_16x16x32_bf16
#pragma unroll
    for (int dt = 0; dt < 8; ++dt) {
        f32x4 acc = {0.f, 0.f, 0.f, 0.f};
        const int od = dt * 16 + (lane & 15);
#pragma unroll
        for (int s = 0; s < 4; ++s) {
            int byte = od * 256 + ((s * 64 + q * 16) ^ ((od & 7) << 4));
            bf16x8 a = *reinterpret_cast<const bf16x8*>(Wl + byte);
            acc = __builtin_amdgcn_mfma_f32_16x16x32_bf16(a, xb[s], acc, 0, 0, 0);
        }
        if (node < N_NODES) {
            unsigned int lo = (unsigned int)f2bf(acc[0]) | ((unsigned int)f2bf(acc[1]) << 16);
            unsigned int hi = (unsigned int)f2bf(acc[2]) | ((unsigned int)f2bf(acc[3]) << 16);
            *reinterpret_cast<uint2*>(h + (size_t)node * DIM + dt * 16 + q * 4) = make_uint2(lo, hi);
        }
    }
}

// ---------------- scan1: per-block exclusive scan of cnt -> off, sums -> bsum, re-zero cnt
__global__ __launch_bounds__(SCAN_BLK) void scan1_kernel(int* __restrict__ cnt,
                                                         int* __restrict__ off,
                                                         int* __restrict__ bsum) {
    __shared__ int s[SCAN_BLK];
    int t = threadIdx.x;
    int i = blockIdx.x * SCAN_BLK + t;
    int v = (i < N_NODES) ? cnt[i] : 0;
    if (i < N_NODES) cnt[i] = 0;                 // re-zero for scatter pass
    s[t] = v;
    __syncthreads();
    for (int d = 1; d < SCAN_BLK; d <<= 1) {
        int add = (t >= d) ? s[t - d] : 0;
        __syncthreads();
        s[t] += add;
        __syncthreads();
    }
    if (i < N_NODES) off[i] = s[t] - v;          // exclusive within block
    if (t == SCAN_BLK - 1) bsum[blockIdx.x] = s[t];
}

// ---------------- scan2: exclusive scan of the 196 block sums (single block)
__global__ __launch_bounds__(SCAN_BLK) void scan2_kernel(int* __restrict__ bsum) {
    __shared__ int s[SCAN_BLK];
    int t = threadIdx.x;
    int v = (t < NSCAN) ? bsum[t] : 0;
    s[t] = v;
    __syncthreads();
    for (int d = 1; d < SCAN_BLK; d <<= 1) {
        int add = (t >= d) ? s[t - d] : 0;
        __syncthreads();
        s[t] += add;
        __syncthreads();
    }
    if (t < NSCAN) bsum[t] = s[t] - v;           // exclusive
}

// ---------------- scatter: pack {col, val} into CSR order
__global__ __launch_bounds__(256) void scatter_kernel(const int* __restrict__ rows,
                                                      const int* __restrict__ cols,
                                                      const float* __restrict__ vals,
                                                      const int* __restrict__ off,
                                                      const int* __restrict__ bsum,
                                                      int* __restrict__ cnt,
                                                      int2* __restrict__ epack) {
    int e = blockIdx.x * 256 + threadIdx.x;
    if (e >= N_EDGES) return;
    int r = rows[e];
    int p = atomicAdd(&cnt[r], 1);
    int2 pk;
    pk.x = cols[e];
    pk.y = __float_as_int(vals[e]);
    epack[off[r] + bsum[r >> 8] + p] = pk;
}

// ---------------- gather: one wave per node, 4-deep pipelined, fused ReLU
__global__ __launch_bounds__(256) void gather_kernel(const unsigned short* __restrict__ h,
                                                     const int2* __restrict__ epack,
                                                     const int* __restrict__ off,
                                                     const int* __restrict__ bsum,
                                                     float* __restrict__ out) {
    int wave = threadIdx.x >> 6;
    int lane = threadIdx.x & 63;
    int n = blockIdx.x * 4 + wave;
    if (n >= N_NODES) return;
    int beg = off[n] + bsum[n >> 8];
    int end = (n + 1 < N_NODES) ? off[n + 1] + bsum[(n + 1) >> 8] : N_EDGES;

    float ax = 0.f, ay = 0.f;
    int i = beg;
    for (; i + 4 <= end; i += 4) {
        int2 e0 = epack[i], e1 = epack[i + 1], e2 = epack[i + 2], e3 = epack[i + 3];
        ushort2 a0 = *((const ushort2*)(h + (size_t)e0.x * DIM) + lane);
        ushort2 a1 = *((const ushort2*)(h + (size_t)e1.x * DIM) + lane);
        ushort2 a2 = *((const ushort2*)(h + (size_t)e2.x * DIM) + lane);
        ushort2 a3 = *((const ushort2*)(h + (size_t)e3.x * DIM) + lane);
        float v0 = __int_as_float(e0.y), v1 = __int_as_float(e1.y);
        float v2 = __int_as_float(e2.y), v3 = __int_as_float(e3.y);
        ax += v0 * bf2f(a0.x) + v1 * bf2f(a1.x) + v2 * bf2f(a2.x) + v3 * bf2f(a3.x);
        ay += v0 * bf2f(a0.y) + v1 * bf2f(a1.y) + v2 * bf2f(a2.y) + v3 * bf2f(a3.y);
    }
    for (; i < end; ++i) {
        int2 e0 = epack[i];
        ushort2 a0 = *((const ushort2*)(h + (size_t)e0.x * DIM) + lane);
        float v0 = __int_as_float(e0.y);
        ax += v0 * bf2f(a0.x);
        ay += v0 * bf2f(a0.y);
    }
    float2 r;
    r.x = fmaxf(ax, 0.f);
    r.y = fmaxf(ay, 0.f);
    *reinterpret_cast<float2*>(&out[(size_t)n * DIM + lane * 2]) = r;
}

// ---------------- fallback: atomic scatter over bf16 h
__global__ __launch_bounds__(256) void edge_kernel(const unsigned short* __restrict__ h,
                                                   const float* __restrict__ vals,
                                                   const int* __restrict__ rows,
                                                   const int* __restrict__ cols,
                                                   float* __restrict__ out) {
    long long gid = (long long)blockIdx.x * 256 + threadIdx.x;
    int e    = (int)(gid >> 5);
    int lane = (int)(gid & 31);
    if (e >= N_EDGES) return;
    int r = rows[e];
    int c = cols[e];
    float v = vals[e];
    ushort4 hv = *((const ushort4*)(h + (size_t)c * DIM) + lane);
    float* op = &out[(size_t)r * DIM + lane * 4];
    atomicAdd(op + 0, v * bf2f(hv.x));
    atomicAdd(op + 1, v * bf2f(hv.y));
    atomicAdd(op + 2, v * bf2f(hv.z));
    atomicAdd(op + 3, v * bf2f(hv.w));
}

__global__ __launch_bounds__(256) void relu_kernel(float* __restrict__ out) {
    int i = blockIdx.x * 256 + threadIdx.x;
    float4* p = reinterpret_cast<float4*>(out) + i;
    float4 v = *p;
    v.x = fmaxf(v.x, 0.f);
    v.y = fmaxf(v.y, 0.f);
    v.z = fmaxf(v.z, 0.f);
    v.w = fmaxf(v.w, 0.f);
    *p = v;
}

extern "C" void kernel_launch(void* const* d_in, const int* in_sizes, int n_in,
                              void* d_out, int out_size, void* d_ws, size_t ws_size,
                              hipStream_t stream) {
    const float* x    = (const float*)d_in[0];
    const float* W    = (const float*)d_in[1];
    const float* vals = (const float*)d_in[2];
    const int*   rows = (const int*)d_in[3];
    const int*   cols = (const int*)d_in[4];
    float* out = (float*)d_out;

    // ---- workspace layout ----
    unsigned short* h = (unsigned short*)d_ws;               // 12.8 MB bf16
    int2* epack = (int2*)(h + (size_t)N_NODES * DIM);        // 4.8 MB
    int*  cnt   = (int*)(epack + N_EDGES);                   // 50000
    int*  off   = cnt + N_NODES;                             // 50000
    int*  bsum  = off + N_NODES;                             // 196
    size_t need = (size_t)((char*)(bsum + NSCAN) - (char*)d_ws);

    if (ws_size >= need) {
        hipMemsetAsync(cnt, 0, N_NODES * sizeof(int), stream);
        // h = bf16(x @ W^T) via MFMA, cnt = row histogram (fused)
        gemm_kernel<<<GEMM_BLOCKS, 256, 0, stream>>>(x, W, h, rows, cnt);
        scan1_kernel<<<NSCAN, SCAN_BLK, 0, stream>>>(cnt, off, bsum);
        scan2_kernel<<<1, SCAN_BLK, 0, stream>>>(bsum);
        scatter_kernel<<<(N_EDGES + 255) / 256, 256, 0, stream>>>(rows, cols, vals, off, bsum, cnt, epack);
        gather_kernel<<<(N_NODES + 3) / 4, 256, 0, stream>>>(h, epack, off, bsum, out);
    } else {
        // fallback: atomic scatter path (needs only h)
        gemm_kernel<<<GEMM_BLOCKS, 256, 0, stream>>>(x, W, h, rows, (int*)nullptr);
        hipMemsetAsync(d_out, 0, (size_t)N_NODES * DIM * sizeof(float), stream);
        edge_kernel<<<(N_EDGES * 32) / 256, 256, 0, stream>>>(h, vals, rows, cols, out);
        relu_kernel<<<(N_NODES * DIM / 4) / 256, 256, 0, stream>>>(out);
    }
}

// Round 5
// 115.059 us; speedup vs baseline: 9.2949x; 1.0043x over previous
//
#include <hip/hip_runtime.h>
#include <hip/hip_fp16.h>

#define N_NODES 50000
#define N_EDGES 600000
#define DIM 128
#define SCAN_BLK 256
#define NSCAN ((N_NODES + SCAN_BLK - 1) / SCAN_BLK)   // 196

typedef short bf16x8 __attribute__((ext_vector_type(8)));
typedef float f32x4 __attribute__((ext_vector_type(4)));

__device__ __forceinline__ float bf2f(unsigned short u) {
    union { unsigned int i; float f; } x; x.i = ((unsigned int)u) << 16; return x.f;
}
__device__ __forceinline__ unsigned short f2bf(float f) {
    union { float f; unsigned int i; } x; x.f = f;
    unsigned int r = x.i + 0x7FFFu + ((x.i >> 16) & 1u);   // RNE
    return (unsigned short)(r >> 16);
}

// ---------------- histogram: standalone, fire-and-forget atomics ----------------
__global__ __launch_bounds__(256) void hist_kernel(const int* __restrict__ rows,
                                                   int* __restrict__ cnt) {
    int e = blockIdx.x * 256 + threadIdx.x;
    if (e < N_EDGES) atomicAdd(&cnt[rows[e]], 1);
}

// ---------------- MFMA GEMM with FUSED CSR scatter ----------------
// h[n][d] = bf16( sum_k x[n][k] * W[d][k] ), fp32 MFMA accumulate.
// A = W-tile, B = x-tile so C/D layout (col=lane&15 -> node, row -> 4
// consecutive dims) gives packed coalesced 8B stores.
// Fused scatter: each thread places 3 edges into CSR order as 4B records
// {val_fp16[31:16] | col_u16[15:0]} — its atomic+write latency hides under
// W-staging and MFMA work.
#define GEMM_BLOCKS ((N_NODES + 63) / 64)           // 782
#define GEMM_THREADS (GEMM_BLOCKS * 256)            // 200192

__global__ __launch_bounds__(256) void gemm_kernel(const float* __restrict__ x,
                                                   const float* __restrict__ W,
                                                   unsigned short* __restrict__ h,
                                                   const int* __restrict__ rows,
                                                   const int* __restrict__ cols,
                                                   const float* __restrict__ vals,
                                                   const int* __restrict__ off,
                                                   const int* __restrict__ bsum,
                                                   int* __restrict__ cnt,
                                                   unsigned int* __restrict__ epack) {
    __shared__ unsigned char Wl[128 * 256];   // bf16[128 dims][128 k], swizzled
    const int tid = threadIdx.x;

    // ---- fused scatter: 3 edges/thread
    if (epack) {
        int g = blockIdx.x * 256 + tid;
#pragma unroll
        for (int it = 0; it < 3; ++it) {
            int e = g + it * GEMM_THREADS;
            if (e < N_EDGES) {
                int r = rows[e];
                unsigned int pk = (unsigned int)cols[e] |
                                  ((unsigned int)__half_as_ushort(__float2half(vals[e])) << 16);
                int p = atomicAdd(&cnt[r], 1);
                epack[off[r] + bsum[r >> 8] + p] = pk;
            }
        }
    }

    // ---- stage W -> LDS bf16 (swizzled): 4096 float4 chunks, 16 per thread
#pragma unroll
    for (int i = 0; i < 16; ++i) {
        int c  = tid + i * 256;
        int od = c >> 5;                 // out dim (W row)
        int kg = c & 31;                 // float4 group: k0 = kg*4
        float4 w = *((const float4*)(W + od * DIM) + kg);
        unsigned int lo = (unsigned int)f2bf(w.x) | ((unsigned int)f2bf(w.y) << 16);
        unsigned int hi = (unsigned int)f2bf(w.z) | ((unsigned int)f2bf(w.w) << 16);
        int byte = od * 256 + ((kg * 8) ^ ((od & 7) << 4));
        *reinterpret_cast<uint2*>(Wl + byte) = make_uint2(lo, hi);
    }

    // ---- load + convert this wave's x rows (node = lane&15, k-slot = lane>>4)
    const int lane = tid & 63;
    const int wv   = tid >> 6;
    const int q    = lane >> 4;
    const int node = blockIdx.x * 64 + wv * 16 + (lane & 15);
    const int ncl  = node < N_NODES ? node : N_NODES - 1;

    bf16x8 xb[4];
#pragma unroll
    for (int s = 0; s < 4; ++s) {
        const float* xp = x + (size_t)ncl * DIM + s * 32 + q * 8;
        float4 x0 = *(const float4*)(xp);
        float4 x1 = *(const float4*)(xp + 4);
        bf16x8 v;
        v[0] = (short)f2bf(x0.x); v[1] = (short)f2bf(x0.y);
        v[2] = (short)f2bf(x0.z); v[3] = (short)f2bf(x0.w);
        v[4] = (short)f2bf(x1.x); v[5] = (short)f2bf(x1.y);
        v[6] = (short)f2bf(x1.z); v[7] = (short)f2bf(x1.w);
        xb[s] = v;
    }

    __syncthreads();

    // ---- 8 dim-tiles x 4 k-steps of mfma_f32_16x16x32_bf16
#pragma unroll
    for (int dt = 0; dt < 8; ++dt) {
        f32x4 acc = {0.f, 0.f, 0.f, 0.f};
        const int od = dt * 16 + (lane & 15);
#pragma unroll
        for (int s = 0; s < 4; ++s) {
            int byte = od * 256 + ((s * 64 + q * 16) ^ ((od & 7) << 4));
            bf16x8 a = *reinterpret_cast<const bf16x8*>(Wl + byte);
            acc = __builtin_amdgcn_mfma_f32_16x16x32_bf16(a, xb[s], acc, 0, 0, 0);
        }
        if (node < N_NODES) {
            unsigned int lo = (unsigned int)f2bf(acc[0]) | ((unsigned int)f2bf(acc[1]) << 16);
            unsigned int hi = (unsigned int)f2bf(acc[2]) | ((unsigned int)f2bf(acc[3]) << 16);
            *reinterpret_cast<uint2*>(h + (size_t)node * DIM + dt * 16 + q * 4) = make_uint2(lo, hi);
        }
    }
}

// ---------------- scan1: per-block exclusive scan of cnt -> off, sums -> bsum, re-zero cnt
__global__ __launch_bounds__(SCAN_BLK) void scan1_kernel(int* __restrict__ cnt,
                                                         int* __restrict__ off,
                                                         int* __restrict__ bsum) {
    __shared__ int s[SCAN_BLK];
    int t = threadIdx.x;
    int i = blockIdx.x * SCAN_BLK + t;
    int v = (i < N_NODES) ? cnt[i] : 0;
    if (i < N_NODES) cnt[i] = 0;                 // re-zero for the fused scatter
    s[t] = v;
    __syncthreads();
    for (int d = 1; d < SCAN_BLK; d <<= 1) {
        int add = (t >= d) ? s[t - d] : 0;
        __syncthreads();
        s[t] += add;
        __syncthreads();
    }
    if (i < N_NODES) off[i] = s[t] - v;          // exclusive within block
    if (t == SCAN_BLK - 1) bsum[blockIdx.x] = s[t];
}

// ---------------- scan2: exclusive scan of the 196 block sums (single block)
__global__ __launch_bounds__(SCAN_BLK) void scan2_kernel(int* __restrict__ bsum) {
    __shared__ int s[SCAN_BLK];
    int t = threadIdx.x;
    int v = (t < NSCAN) ? bsum[t] : 0;
    s[t] = v;
    __syncthreads();
    for (int d = 1; d < SCAN_BLK; d <<= 1) {
        int add = (t >= d) ? s[t - d] : 0;
        __syncthreads();
        s[t] += add;
        __syncthreads();
    }
    if (t < NSCAN) bsum[t] = s[t] - v;           // exclusive
}

// ---------------- gather: one wave per node, 4-deep pipelined, fused ReLU
__global__ __launch_bounds__(256) void gather_kernel(const unsigned short* __restrict__ h,
                                                     const unsigned int* __restrict__ epack,
                                                     const int* __restrict__ off,
                                                     const int* __restrict__ bsum,
                                                     float* __restrict__ out) {
    int wave = threadIdx.x >> 6;
    int lane = threadIdx.x & 63;
    int n = blockIdx.x * 4 + wave;
    if (n >= N_NODES) return;
    int beg = off[n] + bsum[n >> 8];
    int end = (n + 1 < N_NODES) ? off[n + 1] + bsum[(n + 1) >> 8] : N_EDGES;

    float ax = 0.f, ay = 0.f;
    int i = beg;
    for (; i + 4 <= end; i += 4) {
        unsigned int p0 = epack[i], p1 = epack[i + 1];
        unsigned int p2 = epack[i + 2], p3 = epack[i + 3];
        ushort2 a0 = *((const ushort2*)(h + (size_t)(p0 & 0xFFFFu) * DIM) + lane);
        ushort2 a1 = *((const ushort2*)(h + (size_t)(p1 & 0xFFFFu) * DIM) + lane);
        ushort2 a2 = *((const ushort2*)(h + (size_t)(p2 & 0xFFFFu) * DIM) + lane);
        ushort2 a3 = *((const ushort2*)(h + (size_t)(p3 & 0xFFFFu) * DIM) + lane);
        float v0 = __half2float(__ushort_as_half((unsigned short)(p0 >> 16)));
        float v1 = __half2float(__ushort_as_half((unsigned short)(p1 >> 16)));
        float v2 = __half2float(__ushort_as_half((unsigned short)(p2 >> 16)));
        float v3 = __half2float(__ushort_as_half((unsigned short)(p3 >> 16)));
        ax += v0 * bf2f(a0.x) + v1 * bf2f(a1.x) + v2 * bf2f(a2.x) + v3 * bf2f(a3.x);
        ay += v0 * bf2f(a0.y) + v1 * bf2f(a1.y) + v2 * bf2f(a2.y) + v3 * bf2f(a3.y);
    }
    for (; i < end; ++i) {
        unsigned int p0 = epack[i];
        ushort2 a0 = *((const ushort2*)(h + (size_t)(p0 & 0xFFFFu) * DIM) + lane);
        float v0 = __half2float(__ushort_as_half((unsigned short)(p0 >> 16)));
        ax += v0 * bf2f(a0.x);
        ay += v0 * bf2f(a0.y);
    }
    float2 r;
    r.x = fmaxf(ax, 0.f);
    r.y = fmaxf(ay, 0.f);
    *reinterpret_cast<float2*>(&out[(size_t)n * DIM + lane * 2]) = r;
}

// ---------------- fallback: atomic scatter over bf16 h
__global__ __launch_bounds__(256) void edge_kernel(const unsigned short* __restrict__ h,
                                                   const float* __restrict__ vals,
                                                   const int* __restrict__ rows,
                                                   const int* __restrict__ cols,
                                                   float* __restrict__ out) {
    long long gid = (long long)blockIdx.x * 256 + threadIdx.x;
    int e    = (int)(gid >> 5);
    int lane = (int)(gid & 31);
    if (e >= N_EDGES) return;
    int r = rows[e];
    int c = cols[e];
    float v = vals[e];
    ushort4 hv = *((const ushort4*)(h + (size_t)c * DIM) + lane);
    float* op = &out[(size_t)r * DIM + lane * 4];
    atomicAdd(op + 0, v * bf2f(hv.x));
    atomicAdd(op + 1, v * bf2f(hv.y));
    atomicAdd(op + 2, v * bf2f(hv.z));
    atomicAdd(op + 3, v * bf2f(hv.w));
}

__global__ __launch_bounds__(256) void relu_kernel(float* __restrict__ out) {
    int i = blockIdx.x * 256 + threadIdx.x;
    float4* p = reinterpret_cast<float4*>(out) + i;
    float4 v = *p;
    v.x = fmaxf(v.x, 0.f);
    v.y = fmaxf(v.y, 0.f);
    v.z = fmaxf(v.z, 0.f);
    v.w = fmaxf(v.w, 0.f);
    *p = v;
}

extern "C" void kernel_launch(void* const* d_in, const int* in_sizes, int n_in,
                              void* d_out, int out_size, void* d_ws, size_t ws_size,
                              hipStream_t stream) {
    const float* x    = (const float*)d_in[0];
    const float* W    = (const float*)d_in[1];
    const float* vals = (const float*)d_in[2];
    const int*   rows = (const int*)d_in[3];
    const int*   cols = (const int*)d_in[4];
    float* out = (float*)d_out;

    // ---- workspace layout ----
    unsigned short* h = (unsigned short*)d_ws;               // 12.8 MB bf16
    unsigned int* epack = (unsigned int*)(h + (size_t)N_NODES * DIM);  // 2.4 MB
    int*  cnt   = (int*)(epack + N_EDGES);                   // 50000
    int*  off   = cnt + N_NODES;                             // 50000
    int*  bsum  = off + N_NODES;                             // 196
    size_t need = (size_t)((char*)(bsum + NSCAN) - (char*)d_ws);

    if (ws_size >= need) {
        hipMemsetAsync(cnt, 0, N_NODES * sizeof(int), stream);
        hist_kernel<<<(N_EDGES + 255) / 256, 256, 0, stream>>>(rows, cnt);
        scan1_kernel<<<NSCAN, SCAN_BLK, 0, stream>>>(cnt, off, bsum);
        scan2_kernel<<<1, SCAN_BLK, 0, stream>>>(bsum);
        // h = bf16(x @ W^T) via MFMA, with the CSR scatter fused in
        gemm_kernel<<<GEMM_BLOCKS, 256, 0, stream>>>(x, W, h, rows, cols, vals,
                                                     off, bsum, cnt, epack);
        gather_kernel<<<(N_NODES + 3) / 4, 256, 0, stream>>>(h, epack, off, bsum, out);
    } else {
        // fallback: atomic scatter path (needs only h)
        gemm_kernel<<<GEMM_BLOCKS, 256, 0, stream>>>(x, W, h, nullptr, nullptr, nullptr,
                                                     nullptr, nullptr, nullptr, nullptr);
        hipMemsetAsync(d_out, 0, (size_t)N_NODES * DIM * sizeof(float), stream);
        edge_kernel<<<(N_EDGES * 32) / 256, 256, 0, stream>>>(h, vals, rows, cols, out);
        relu_kernel<<<(N_NODES * DIM / 4) / 256, 256, 0, stream>>>(out);
    }
}